// Round 6
// baseline (212.556 us; speedup 1.0000x reference)
//
#include <hip/hip_runtime.h>

// PrimalDualNetwork: 10-iter Chambolle-Pock ROF on 2048x2048 fp32.
// R14 = R12 verbatim (tile 64x32, NT=512, NPASS=3, grid 32x64=2048
// blocks) with launch_bounds(512, 8) -- the single untested quadrant:
//  - Empirical law from R9-R13: resident waves/CU = 4 x launch_bounds
//    2nd arg, regardless of resources. (512,4)/(1024,4) -> 16 waves
//    (occ 33-40%); (1024,8) -> 32 waves (occ 63%, best dur despite
//    spilling). Residency, not codegen, dominated every delta.
//  - Codegen pathology is BLOCK-SIZE-driven: 16-wave blocks at arg 8
//    gave the 32-VGPR spilling allocation; 8-wave blocks gave clean
//    48-VGPR twice (R9, R12). So: 8-wave blocks + arg 8 = proven-clean
//    codegen at full residency. Budget 512/8 = 64 >= 48 natural.
//  - grid 2048 = 4 blocks/CU x 256 CU x exactly 2 uniform rounds.
//  - LDS 20.6 KB x 4 blocks = 84 KB < 160 KB; 48 VGPR x 8 waves/SIMD
//    = 384 <= 512.
// Tripwires: VGPR=32 / WRITE_SIZE ~40 MB => spill pathology is
// arg-driven -> next step is 32-VGPR state diet. Occ stays ~40% =>
// residency law wrong.
// All R9 numerics unchanged: x (primal) fp32 in registers, xt fp16
// plane, cone guard, demasked sw, final primal stores fp32 to global.

namespace {
constexpr int M = 2048, N = 2048;
constexpr float SIGMA     = 1.0f / (7.0f * 0.01f);
constexpr float TAUIS     = 0.01f * (7.0f * 0.01f);  // tau/sigma
constexpr float LT        = 4.0f * 0.01f;
constexpr float INV_DEN   = 1.0f / (1.0f + 4.0f * 0.01f);
constexpr int TW = 64, TH = 32;     // output tile
constexpr int PC = 88;              // plane cols (12 + 64 + 12)
constexpr int PR = 52;              // plane rows (10 + 32 + 10)
constexpr int UPR = 22;             // h4 units per row == PC/4
constexpr int PROC = 51;            // rows 0..50 processed (51 read-only)
constexpr int NU = PROC * UPR;      // 1122
constexpr int NT = 512;             // 8 waves
constexpr int NPASS = 3;            // 3*512=1536 >= NU and >= PR*UPR=1144
constexpr int GY = M / TH;          // 64  (exact: no partial tiles)
} // namespace

typedef _Float16 h4 __attribute__((ext_vector_type(4)));
typedef unsigned uint32;

__device__ inline h4 h4splat(float v) {
    _Float16 s = (_Float16)v;
    return (h4){s, s, s, s};
}
__device__ inline int imax(int a, int b) { return a > b ? a : b; }
__device__ inline uint32 abit(uint32 hi, uint32 lo) {
    return __builtin_amdgcn_alignbit(hi, lo, 16);
}
__device__ inline h4 clamp1(h4 v) {
    return __builtin_elementwise_min(
               __builtin_elementwise_max(v, h4splat(-1.f)), h4splat(1.f));
}

__global__ __launch_bounds__(NT, 8) void pd_fused(
    const float* __restrict__ img, float* __restrict__ out,
    const float* __restrict__ w1p, const float* __restrict__ w2p)
{
    __shared__ __align__(16) _Float16 sXT16[PR * PC];  // 9152 B (xt, fp16)
    __shared__ __align__(16) _Float16 sQV[PR * PC];    // 9152 B
    __shared__ __align__(16) _Float16 sQH3[1136];      // 2272 B (qH[3]/unit)

    const int tid  = threadIdx.x;
    const int lane = tid & 63;
    const int c0 = blockIdx.x * TW, r0 = blockIdx.y * TH;
    const int gr0 = r0 - 10, gc0 = c0 - 12;
    const float w1 = w1p[0], w2 = w2p[0];

    // cone deactivation threshold per pass (active iff rem >= d)
    int dth_[NPASS];
    #pragma unroll
    for (int p = 0; p < NPASS; ++p) {
        int u = tid + p * NT;
        int li = u / UPR, lc = (u - li * UPR) * 4;
        int d = imax(imax(9 - li, li - (TH + 9)), imax(8 - lc, lc - 75));
        d = imax(d, 0);
        if (u >= NU) d = 100;
        dth_[p] = d;
    }

    // ---- stage img -> sXT16 (fp16; 0 outside image) ----
    #pragma unroll
    for (int p = 0; p < NPASS; ++p) {
        int su = tid + p * NT;
        if (su < PR * UPR) {
            int li = su / UPR, uj = su - li * UPR;
            int gi = gr0 + li, gj = gc0 + uj * 4;
            float4 v = make_float4(0.f, 0.f, 0.f, 0.f);
            if ((unsigned)gi < (unsigned)M && (unsigned)gj <= (unsigned)(N - 4))
                v = *(const float4*)&img[(size_t)gi * N + gj];
            h4 h; h[0] = (_Float16)v.x; h[1] = (_Float16)v.y;
                  h[2] = (_Float16)v.z; h[3] = (_Float16)v.w;
            *(h4*)&sXT16[su * 4] = h;
        }
    }
    __syncthreads();

    // register state: x fp32 (precision-critical), rest packed fp16
    float xr[NPASS][4];
    h4 xt16[NPASS], xi16[NPASS], yh[NPASS], yv[NPASS],
       swh[NPASS], swv[NPASS], qH[NPASS];

    // ---- init (== dual(0)): masked sigma*w, y0, q0 ----
    #pragma unroll
    for (int p = 0; p < NPASS; ++p) {
        int u = tid + p * NT;
        if (u < NU) {
            int bF = u * 4;
            int li = u / UPR;
            int gi = gr0 + li, gjb = gc0 + (u - li * UPR) * 4;
            h4 c16 = *(const h4*)&sXT16[bF];
            uint32 rrp = *(const uint32*)&sXT16[bF + 4];
            h4 dn = *(const h4*)&sXT16[bF + PC];
            uint2 xu = __builtin_bit_cast(uint2, c16);
            h4 xsh = __builtin_bit_cast(h4,
                         make_uint2(abit(xu.y, xu.x), abit(rrp, xu.y)));
            bool rok = (unsigned)gi < (unsigned)M;
            bool vok = rok && (gi < M - 1);
            h4 qv;
            #pragma unroll
            for (int l = 0; l < 4; ++l) {
                int gj = gjb + l;
                bool cok = (unsigned)gj < (unsigned)N;
                bool hok = rok && cok && (gj < N - 1);
                bool vk  = vok && cok;
                float ghf = hok ? (float)xsh[l] - (float)c16[l] : 0.f;
                float gvf = vk  ? (float)dn[l]  - (float)c16[l] : 0.f;
                float wh = fmaf(w2, __expf(-fabsf(ghf)), w1);
                float wv = fmaf(w2, __expf(-fabsf(gvf)), w1);
                float y0h = fminf(fmaxf(ghf * fmaf(SIGMA, wh, 1.f), -1.f), 1.f);
                float y0v = fminf(fmaxf(gvf * fmaf(SIGMA, wv, 1.f), -1.f), 1.f);
                float sh = hok ? SIGMA * wh : 0.f;
                float sv = vk  ? SIGMA * wv : 0.f;
                yh[p][l]  = (_Float16)y0h;  yv[p][l]  = (_Float16)y0v;
                swh[p][l] = (_Float16)sh;   swv[p][l] = (_Float16)sv;
                qH[p][l]  = (_Float16)(sh * y0h);
                qv[l]     = (_Float16)(sv * y0v);
                xr[p][l]  = (float)c16[l];
            }
            xi16[p] = c16; xt16[p] = c16;
            *(h4*)&sQV[bF] = qv;
            sQH3[u] = qH[p][3];
        }
    }
    __syncthreads();

    // ---- dual(t>=1): fully packed; y = clamp(y + sw*grad16(xt)); q = sw*y
    auto dual = [&](int rem) {
        #pragma unroll
        for (int p = 0; p < NPASS; ++p) {
            uint2 xu = __builtin_bit_cast(uint2, xt16[p]);
            uint32 rrp = __shfl_down(xu.x, 1, 64);   // hoisted (exec-safe)
            if (rem >= dth_[p]) {
                int bF = (tid + p * NT) * 4;
                if (lane == 63) rrp = *(const uint32*)&sXT16[bF + 4];
                h4 dn = *(const h4*)&sXT16[bF + PC];
                h4 xsh = __builtin_bit_cast(h4,
                             make_uint2(abit(xu.y, xu.x), abit(rrp, xu.y)));
                h4 ghh = xsh - xt16[p];              // v_pk_sub_f16
                h4 gvh = dn  - xt16[p];
                h4 nh = clamp1(yh[p] + swh[p] * ghh);  // sw=0 masks borders
                h4 nv = clamp1(yv[p] + swv[p] * gvh);
                yh[p] = nh; yv[p] = nv;
                h4 qh = swh[p] * nh;                 // q = sigma*w*y
                h4 qv = swv[p] * nv;
                qH[p] = qh;
                *(h4*)&sQV[bF] = qv;
                sQH3[bF >> 2] = qh[3];
            }
        }
    };

    // ---- primal: x = (x + (tau/sigma)*div(q) + lt*img)/(1+lt);
    //      xt = 1.5x - 0.5xo. last: store fp32 to global, skip LDS. ----
    auto primal = [&](int rem, bool last) {
        #pragma unroll
        for (int p = 0; p < NPASS; ++p) {
            if (rem >= dth_[p]) {
                int u = tid + p * NT, bF = u * 4;
                int bu = (bF >= UPR * 4) ? bF - PC : bF;  // row-0 junk tolerated
                h4 qvu = *(const h4*)&sQV[bu];
                h4 qv  = *(const h4*)&sQV[bF];
                uint32 qhl = *(const unsigned short*)&sQH3[imax(u - 1, 0)];
                uint2 qu = __builtin_bit_cast(uint2, qH[p]);
                h4 qsh = __builtin_bit_cast(h4,
                             make_uint2(abit(qu.x, qhl << 16), abit(qu.y, qu.x)));
                h4 dvg = (qH[p] - qsh) + (qv - qvu);     // v_pk_sub/add_f16
                float xtv[4];
                #pragma unroll
                for (int l = 0; l < 4; ++l) {
                    float dv = (float)dvg[l];
                    float xo = xr[p][l];
                    float xn = (fmaf(TAUIS, dv, xo) + LT * (float)xi16[p][l]) * INV_DEN;
                    xr[p][l] = xn;
                    xtv[l] = fmaf(0.5f, xn - xo, xn);    // 1.5x - 0.5xo
                }
                if (!last) {
                    h4 nx; nx[0] = (_Float16)xtv[0]; nx[1] = (_Float16)xtv[1];
                           nx[2] = (_Float16)xtv[2]; nx[3] = (_Float16)xtv[3];
                    xt16[p] = nx;
                    *(h4*)&sXT16[bF] = nx;
                } else {
                    int li = u / UPR, uj = u - li * UPR;
                    int gi = gr0 + li;
                    if (li >= 10 && uj >= 3 && uj <= 18 && gi < M) {
                        *(float4*)&out[(size_t)gi * N + (gc0 + uj * 4)] =
                            make_float4(xtv[0], xtv[1], xtv[2], xtv[3]);
                    }
                }
            }
        }
    };

    primal(9, false);          // t=0 (dual(0) fused into init)
    __syncthreads();
    #pragma unroll 1
    for (int t = 1; t < 10; ++t) {
        int rem = 9 - t;
        dual(rem);
        __syncthreads();
        primal(rem, t == 9);
        __syncthreads();
    }
}

extern "C" void kernel_launch(void* const* d_in, const int* in_sizes, int n_in,
                              void* d_out, int out_size, void* d_ws, size_t ws_size,
                              hipStream_t stream)
{
    const float* img = (const float*)d_in[0];
    const float* w1  = (const float*)d_in[1];
    const float* w2  = (const float*)d_in[2];
    float* out = (float*)d_out;

    dim3 grid(N / TW, GY);   // 32 x 64 = 2048 blocks = 4/CU x 2 rounds
    pd_fused<<<grid, NT, 0, stream>>>(img, out, w1, w2);
}

// Round 7
// 109.463 us; speedup vs baseline: 1.9418x; 1.9418x over previous
//
#include <hip/hip_runtime.h>

// PrimalDualNetwork: 10-iter Chambolle-Pock ROF on 2048x2048 fp32.
// R15 = R10's proven-best config (tile 64x64, NT=1024, NPASS=2, grid
// 32x32, launch_bounds(1024,8)) + REGISTER DIET to fit the 32-VGPR
// codegen that arg=8 always produces:
//  - Empirical laws from R9-R14: (1) HW residency = 4 x 2nd-arg
//    waves/CU EXACTLY (descriptor-driven; resources never limited);
//    (2) arg=8 => 32-VGPR codegen, always. R10 spilled ~29 MB at
//    36-reg state and STILL won on residency; R14's 54-reg state
//    spilled 434 MB. So: keep arg=8, shrink state below 32.
//  - Moved read-only per-thread state to LDS planes: xi16 (img, read
//    1x/primal), swh/swv (sigma*w masks, read 1x/dual). -12 VGPRs of
//    live-across-barrier state -> ~24 named regs + temps, fits 32.
//    Cost: 3 ds_read_b64 per unit-iter, conflict-free (consecutive
//    lanes -> consecutive 8B, 2-way aliasing = free).
//  - LDS: 5 planes x 14784 + 3680 = 77.6 KB/block; 2 blocks/CU =
//    155.2 KB <= 160 KB. Tripwire: Occ ~31% => LDS limited us to
//    1 block/CU -> drop sIMG plane next.
//  - Tripwire: WRITE_SIZE >> 16384 KB => diet insufficient, spills
//    persist.
// Numerics unchanged: x (primal) fp32 in registers, xt fp16 plane,
// cone guard, demasked sw, final primal stores fp32 to global.

namespace {
constexpr int M = 2048, N = 2048;
constexpr float SIGMA     = 1.0f / (7.0f * 0.01f);
constexpr float TAUIS     = 0.01f * (7.0f * 0.01f);  // tau/sigma
constexpr float LT        = 4.0f * 0.01f;
constexpr float INV_DEN   = 1.0f / (1.0f + 4.0f * 0.01f);
constexpr int TW = 64, TH = 64;     // output tile
constexpr int PC = 88;              // plane cols (12 + 64 + 12)
constexpr int PR = 84;              // plane rows (10 + 64 + 10)
constexpr int UPR = 22;             // h4 units per row == PC/4
constexpr int PROC = 83;            // rows 0..82 processed (83 read-only)
constexpr int NU = PROC * UPR;      // 1826
constexpr int NT = 1024;            // 16 waves
constexpr int NPASS = 2;            // 2*1024 >= NU (and >= PR*UPR=1848)
constexpr int GY = M / TH;          // 32  (exact: no partial tiles)
} // namespace

typedef _Float16 h4 __attribute__((ext_vector_type(4)));
typedef unsigned uint32;

__device__ inline h4 h4splat(float v) {
    _Float16 s = (_Float16)v;
    return (h4){s, s, s, s};
}
__device__ inline int imax(int a, int b) { return a > b ? a : b; }
__device__ inline uint32 abit(uint32 hi, uint32 lo) {
    return __builtin_amdgcn_alignbit(hi, lo, 16);
}
__device__ inline h4 clamp1(h4 v) {
    return __builtin_elementwise_min(
               __builtin_elementwise_max(v, h4splat(-1.f)), h4splat(1.f));
}

__global__ __launch_bounds__(NT, 8) void pd_fused(
    const float* __restrict__ img, float* __restrict__ out,
    const float* __restrict__ w1p, const float* __restrict__ w2p)
{
    __shared__ __align__(16) _Float16 sXT16[PR * PC];  // 14784 B (xt, fp16)
    __shared__ __align__(16) _Float16 sQV[PR * PC];    // 14784 B
    __shared__ __align__(16) _Float16 sIMG[PR * PC];   // 14784 B (img, ro)
    __shared__ __align__(16) _Float16 sSWH[PR * PC];   // 14784 B (sw_h, ro)
    __shared__ __align__(16) _Float16 sSWV[PR * PC];   // 14784 B (sw_v, ro)
    __shared__ __align__(16) _Float16 sQH3[1840];      //  3680 B (qH[3]/unit)

    const int tid  = threadIdx.x;
    const int lane = tid & 63;
    const int c0 = blockIdx.x * TW, r0 = blockIdx.y * TH;
    const int gr0 = r0 - 10, gc0 = c0 - 12;
    const float w1 = w1p[0], w2 = w2p[0];

    // cone deactivation threshold per pass (active iff rem >= d)
    int dth_[NPASS];
    #pragma unroll
    for (int p = 0; p < NPASS; ++p) {
        int u = tid + p * NT;
        int li = u / UPR, lc = (u - li * UPR) * 4;
        int d = imax(imax(9 - li, li - (TH + 9)), imax(8 - lc, lc - 75));
        d = imax(d, 0);
        if (u >= NU) d = 100;
        dth_[p] = d;
    }

    // ---- stage img -> sXT16 + sIMG (fp16; 0 outside image) ----
    #pragma unroll
    for (int p = 0; p < NPASS; ++p) {
        int su = tid + p * NT;
        if (su < PR * UPR) {
            int li = su / UPR, uj = su - li * UPR;
            int gi = gr0 + li, gj = gc0 + uj * 4;
            float4 v = make_float4(0.f, 0.f, 0.f, 0.f);
            if ((unsigned)gi < (unsigned)M && (unsigned)gj <= (unsigned)(N - 4))
                v = *(const float4*)&img[(size_t)gi * N + gj];
            h4 h; h[0] = (_Float16)v.x; h[1] = (_Float16)v.y;
                  h[2] = (_Float16)v.z; h[3] = (_Float16)v.w;
            *(h4*)&sXT16[su * 4] = h;
            *(h4*)&sIMG[su * 4]  = h;
        }
    }
    __syncthreads();

    // register state (dieted to fit 32 VGPR): x fp32, xt/y/q packed fp16
    float xr[NPASS][4];
    h4 xt16[NPASS], yh[NPASS], yv[NPASS], qH[NPASS];

    // ---- init (== dual(0)): masked sigma*w -> LDS, y0, q0 ----
    #pragma unroll
    for (int p = 0; p < NPASS; ++p) {
        int u = tid + p * NT;
        if (u < NU) {
            int bF = u * 4;
            int li = u / UPR;
            int gi = gr0 + li, gjb = gc0 + (u - li * UPR) * 4;
            h4 c16 = *(const h4*)&sXT16[bF];
            uint32 rrp = *(const uint32*)&sXT16[bF + 4];
            h4 dn = *(const h4*)&sXT16[bF + PC];
            uint2 xu = __builtin_bit_cast(uint2, c16);
            h4 xsh = __builtin_bit_cast(h4,
                         make_uint2(abit(xu.y, xu.x), abit(rrp, xu.y)));
            bool rok = (unsigned)gi < (unsigned)M;
            bool vok = rok && (gi < M - 1);
            h4 qv, swhv, swvv;
            #pragma unroll
            for (int l = 0; l < 4; ++l) {
                int gj = gjb + l;
                bool cok = (unsigned)gj < (unsigned)N;
                bool hok = rok && cok && (gj < N - 1);
                bool vk  = vok && cok;
                float ghf = hok ? (float)xsh[l] - (float)c16[l] : 0.f;
                float gvf = vk  ? (float)dn[l]  - (float)c16[l] : 0.f;
                float wh = fmaf(w2, __expf(-fabsf(ghf)), w1);
                float wv = fmaf(w2, __expf(-fabsf(gvf)), w1);
                float y0h = fminf(fmaxf(ghf * fmaf(SIGMA, wh, 1.f), -1.f), 1.f);
                float y0v = fminf(fmaxf(gvf * fmaf(SIGMA, wv, 1.f), -1.f), 1.f);
                float sh = hok ? SIGMA * wh : 0.f;
                float sv = vk  ? SIGMA * wv : 0.f;
                yh[p][l]   = (_Float16)y0h;  yv[p][l] = (_Float16)y0v;
                swhv[l]    = (_Float16)sh;   swvv[l]  = (_Float16)sv;
                qH[p][l]   = (_Float16)(sh * y0h);
                qv[l]      = (_Float16)(sv * y0v);
                xr[p][l]   = (float)c16[l];
            }
            xt16[p] = c16;
            *(h4*)&sSWH[bF] = swhv;
            *(h4*)&sSWV[bF] = swvv;
            *(h4*)&sQV[bF]  = qv;
            sQH3[u] = qH[p][3];
        }
    }
    __syncthreads();

    // ---- dual(t>=1): y = clamp(y + sw*grad16(xt)); q = sw*y
    //      (sw sourced from LDS planes -- read-only, 1 read/unit) ----
    auto dual = [&](int rem) {
        #pragma unroll
        for (int p = 0; p < NPASS; ++p) {
            uint2 xu = __builtin_bit_cast(uint2, xt16[p]);
            uint32 rrp = __shfl_down(xu.x, 1, 64);   // hoisted (exec-safe)
            if (rem >= dth_[p]) {
                int bF = (tid + p * NT) * 4;
                if (lane == 63) rrp = *(const uint32*)&sXT16[bF + 4];
                h4 dn  = *(const h4*)&sXT16[bF + PC];
                h4 swh = *(const h4*)&sSWH[bF];
                h4 swv = *(const h4*)&sSWV[bF];
                h4 xsh = __builtin_bit_cast(h4,
                             make_uint2(abit(xu.y, xu.x), abit(rrp, xu.y)));
                h4 ghh = xsh - xt16[p];              // v_pk_sub_f16
                h4 gvh = dn  - xt16[p];
                h4 nh = clamp1(yh[p] + swh * ghh);   // sw=0 masks borders
                h4 nv = clamp1(yv[p] + swv * gvh);
                yh[p] = nh; yv[p] = nv;
                h4 qh = swh * nh;                    // q = sigma*w*y
                h4 qv = swv * nv;
                qH[p] = qh;
                *(h4*)&sQV[bF] = qv;
                sQH3[bF >> 2] = qh[3];
            }
        }
    };

    // ---- primal: x = (x + (tau/sigma)*div(q) + lt*img)/(1+lt);
    //      xt = 1.5x - 0.5xo. img sourced from sIMG plane.
    //      last: store fp32 to global, skip LDS. ----
    auto primal = [&](int rem, bool last) {
        #pragma unroll
        for (int p = 0; p < NPASS; ++p) {
            if (rem >= dth_[p]) {
                int u = tid + p * NT, bF = u * 4;
                int bu = (bF >= UPR * 4) ? bF - PC : bF;  // row-0 junk tolerated
                h4 qvu = *(const h4*)&sQV[bu];
                h4 qv  = *(const h4*)&sQV[bF];
                h4 xi  = *(const h4*)&sIMG[bF];
                uint32 qhl = *(const unsigned short*)&sQH3[imax(u - 1, 0)];
                uint2 qu = __builtin_bit_cast(uint2, qH[p]);
                h4 qsh = __builtin_bit_cast(h4,
                             make_uint2(abit(qu.x, qhl << 16), abit(qu.y, qu.x)));
                h4 dvg = (qH[p] - qsh) + (qv - qvu);     // v_pk_sub/add_f16
                float xtv[4];
                #pragma unroll
                for (int l = 0; l < 4; ++l) {
                    float dv = (float)dvg[l];
                    float xo = xr[p][l];
                    float xn = (fmaf(TAUIS, dv, xo) + LT * (float)xi[l]) * INV_DEN;
                    xr[p][l] = xn;
                    xtv[l] = fmaf(0.5f, xn - xo, xn);    // 1.5x - 0.5xo
                }
                if (!last) {
                    h4 nx; nx[0] = (_Float16)xtv[0]; nx[1] = (_Float16)xtv[1];
                           nx[2] = (_Float16)xtv[2]; nx[3] = (_Float16)xtv[3];
                    xt16[p] = nx;
                    *(h4*)&sXT16[bF] = nx;
                } else {
                    int li = u / UPR, uj = u - li * UPR;
                    int gi = gr0 + li;
                    if (li >= 10 && uj >= 3 && uj <= 18 && gi < M) {
                        *(float4*)&out[(size_t)gi * N + (gc0 + uj * 4)] =
                            make_float4(xtv[0], xtv[1], xtv[2], xtv[3]);
                    }
                }
            }
        }
    };

    primal(9, false);          // t=0 (dual(0) fused into init)
    __syncthreads();
    #pragma unroll 1
    for (int t = 1; t < 10; ++t) {
        int rem = 9 - t;
        dual(rem);
        __syncthreads();
        primal(rem, t == 9);
        __syncthreads();
    }
}

extern "C" void kernel_launch(void* const* d_in, const int* in_sizes, int n_in,
                              void* d_out, int out_size, void* d_ws, size_t ws_size,
                              hipStream_t stream)
{
    const float* img = (const float*)d_in[0];
    const float* w1  = (const float*)d_in[1];
    const float* w2  = (const float*)d_in[2];
    float* out = (float*)d_out;

    dim3 grid(N / TW, GY);   // 32 x 32 = 1024 blocks = 2/CU x 512 slots
    pd_fused<<<grid, NT, 0, stream>>>(img, out, w1, w2);
}

// Round 8
// 107.867 us; speedup vs baseline: 1.9705x; 1.0148x over previous
//
#include <hip/hip_runtime.h>

// PrimalDualNetwork: 10-iter Chambolle-Pock ROF on 2048x2048 fp32.
// R16 = R15 (tile 64x64, NT=1024, NPASS=2, arg=8 -> 32 waves/CU, LDS
// planes for read-only state, 32-VGPR codegen) + VALU issue-count diet.
// R15 post-mortem: spills were latency-hidden (removing them didn't
// move dur); kernel is VALU-issue-bound (VALUBusy 62%, HBM 9%).
// Changes, zero structural:
//  1. dual: __shfl_down + lane63 fixup -> one unconditional
//     ds_read_b32 of sXT16[bF+4] (bit-identical: primal writes xt to
//     reg AND LDS; row-edge aliasing unchanged). Kills ds_bpermute +
//     cmp/cndmask per pass.
//  2. sIMG -> sCI = (LT*INV_DEN)*img in fp16: primal folds to
//     xn = fma(INV_DEN, xo, fma(TAUIS*INV_DEN, dv, ci)). ci fp16 err
//     <= 3e-5/iter, ~3e-4 accumulated (absmax budget 0.0177).
//  3. primal fp32 math on float2 ext-vectors (x state f2[2]) ->
//     gfx950 packed-fp32 (v_pk_fma_f32 etc.) halves fp32 issues.
// Tripwire: dur unchanged => latency/barrier-bound -> attack barrier
// structure next. LDS 77.6 KB (5 planes + sQH3), 2 blocks/CU.

namespace {
constexpr int M = 2048, N = 2048;
constexpr float SIGMA     = 1.0f / (7.0f * 0.01f);
constexpr float TAUIS     = 0.01f * (7.0f * 0.01f);  // tau/sigma
constexpr float LT        = 4.0f * 0.01f;
constexpr float INV_DEN   = 1.0f / (1.0f + 4.0f * 0.01f);
constexpr float TAUIS_ID  = TAUIS * INV_DEN;
constexpr float LT_ID     = LT * INV_DEN;
constexpr int TW = 64, TH = 64;     // output tile
constexpr int PC = 88;              // plane cols (12 + 64 + 12)
constexpr int PR = 84;              // plane rows (10 + 64 + 10)
constexpr int UPR = 22;             // h4 units per row == PC/4
constexpr int PROC = 83;            // rows 0..82 processed (83 read-only)
constexpr int NU = PROC * UPR;      // 1826
constexpr int NT = 1024;            // 16 waves
constexpr int NPASS = 2;            // 2*1024 >= NU (and >= PR*UPR=1848)
constexpr int GY = M / TH;          // 32  (exact: no partial tiles)
} // namespace

typedef _Float16 h4 __attribute__((ext_vector_type(4)));
typedef float    f2 __attribute__((ext_vector_type(2)));
typedef unsigned uint32;

__device__ inline h4 h4splat(float v) {
    _Float16 s = (_Float16)v;
    return (h4){s, s, s, s};
}
__device__ inline int imax(int a, int b) { return a > b ? a : b; }
__device__ inline uint32 abit(uint32 hi, uint32 lo) {
    return __builtin_amdgcn_alignbit(hi, lo, 16);
}
__device__ inline h4 clamp1(h4 v) {
    return __builtin_elementwise_min(
               __builtin_elementwise_max(v, h4splat(-1.f)), h4splat(1.f));
}

__global__ __launch_bounds__(NT, 8) void pd_fused(
    const float* __restrict__ img, float* __restrict__ out,
    const float* __restrict__ w1p, const float* __restrict__ w2p)
{
    __shared__ __align__(16) _Float16 sXT16[PR * PC];  // 14784 B (xt, fp16)
    __shared__ __align__(16) _Float16 sQV[PR * PC];    // 14784 B
    __shared__ __align__(16) _Float16 sCI[PR * PC];    // 14784 B (LT_ID*img)
    __shared__ __align__(16) _Float16 sSWH[PR * PC];   // 14784 B (sw_h, ro)
    __shared__ __align__(16) _Float16 sSWV[PR * PC];   // 14784 B (sw_v, ro)
    __shared__ __align__(16) _Float16 sQH3[1840];      //  3680 B (qH[3]/unit)

    const int tid  = threadIdx.x;
    const int c0 = blockIdx.x * TW, r0 = blockIdx.y * TH;
    const int gr0 = r0 - 10, gc0 = c0 - 12;
    const float w1 = w1p[0], w2 = w2p[0];

    // cone deactivation threshold per pass (active iff rem >= d)
    int dth_[NPASS];
    #pragma unroll
    for (int p = 0; p < NPASS; ++p) {
        int u = tid + p * NT;
        int li = u / UPR, lc = (u - li * UPR) * 4;
        int d = imax(imax(9 - li, li - (TH + 9)), imax(8 - lc, lc - 75));
        d = imax(d, 0);
        if (u >= NU) d = 100;
        dth_[p] = d;
    }

    // ---- stage img -> sXT16 (fp16; 0 outside image) ----
    #pragma unroll
    for (int p = 0; p < NPASS; ++p) {
        int su = tid + p * NT;
        if (su < PR * UPR) {
            int li = su / UPR, uj = su - li * UPR;
            int gi = gr0 + li, gj = gc0 + uj * 4;
            float4 v = make_float4(0.f, 0.f, 0.f, 0.f);
            if ((unsigned)gi < (unsigned)M && (unsigned)gj <= (unsigned)(N - 4))
                v = *(const float4*)&img[(size_t)gi * N + gj];
            h4 h; h[0] = (_Float16)v.x; h[1] = (_Float16)v.y;
                  h[2] = (_Float16)v.z; h[3] = (_Float16)v.w;
            *(h4*)&sXT16[su * 4] = h;
        }
    }
    __syncthreads();

    // register state (fits 32 VGPR): x fp32 pairs, xt/y/q packed fp16
    f2 xr2[NPASS][2];
    h4 xt16[NPASS], yh[NPASS], yv[NPASS], qH[NPASS];

    // ---- init (== dual(0)): masked sigma*w -> LDS, ci -> LDS, y0, q0 ----
    #pragma unroll
    for (int p = 0; p < NPASS; ++p) {
        int u = tid + p * NT;
        if (u < NU) {
            int bF = u * 4;
            int li = u / UPR;
            int gi = gr0 + li, gjb = gc0 + (u - li * UPR) * 4;
            h4 c16 = *(const h4*)&sXT16[bF];
            uint32 rrp = *(const uint32*)&sXT16[bF + 4];
            h4 dn = *(const h4*)&sXT16[bF + PC];
            uint2 xu = __builtin_bit_cast(uint2, c16);
            h4 xsh = __builtin_bit_cast(h4,
                         make_uint2(abit(xu.y, xu.x), abit(rrp, xu.y)));
            bool rok = (unsigned)gi < (unsigned)M;
            bool vok = rok && (gi < M - 1);
            h4 qv, swhv, swvv, civ;
            #pragma unroll
            for (int l = 0; l < 4; ++l) {
                int gj = gjb + l;
                bool cok = (unsigned)gj < (unsigned)N;
                bool hok = rok && cok && (gj < N - 1);
                bool vk  = vok && cok;
                float xf  = (float)c16[l];
                float ghf = hok ? (float)xsh[l] - xf : 0.f;
                float gvf = vk  ? (float)dn[l]  - xf : 0.f;
                float wh = fmaf(w2, __expf(-fabsf(ghf)), w1);
                float wv = fmaf(w2, __expf(-fabsf(gvf)), w1);
                float y0h = fminf(fmaxf(ghf * fmaf(SIGMA, wh, 1.f), -1.f), 1.f);
                float y0v = fminf(fmaxf(gvf * fmaf(SIGMA, wv, 1.f), -1.f), 1.f);
                float sh = hok ? SIGMA * wh : 0.f;
                float sv = vk  ? SIGMA * wv : 0.f;
                yh[p][l]   = (_Float16)y0h;  yv[p][l] = (_Float16)y0v;
                swhv[l]    = (_Float16)sh;   swvv[l]  = (_Float16)sv;
                qH[p][l]   = (_Float16)(sh * y0h);
                qv[l]      = (_Float16)(sv * y0v);
                civ[l]     = (_Float16)(LT_ID * xf);
                xr2[p][l >> 1][l & 1] = xf;
            }
            xt16[p] = c16;
            *(h4*)&sSWH[bF] = swhv;
            *(h4*)&sSWV[bF] = swvv;
            *(h4*)&sCI[bF]  = civ;
            *(h4*)&sQV[bF]  = qv;
            sQH3[u] = qH[p][3];
        }
    }
    __syncthreads();

    // ---- dual(t>=1): y = clamp(y + sw*grad16(xt)); q = sw*y
    //      right-neighbor dword read straight from sXT16 (no shfl) ----
    auto dual = [&](int rem) {
        #pragma unroll
        for (int p = 0; p < NPASS; ++p) {
            if (rem >= dth_[p]) {
                int bF = (tid + p * NT) * 4;
                uint32 rrp = *(const uint32*)&sXT16[bF + 4];
                h4 dn  = *(const h4*)&sXT16[bF + PC];
                h4 swh = *(const h4*)&sSWH[bF];
                h4 swv = *(const h4*)&sSWV[bF];
                uint2 xu = __builtin_bit_cast(uint2, xt16[p]);
                h4 xsh = __builtin_bit_cast(h4,
                             make_uint2(abit(xu.y, xu.x), abit(rrp, xu.y)));
                h4 ghh = xsh - xt16[p];              // v_pk_sub_f16
                h4 gvh = dn  - xt16[p];
                h4 nh = clamp1(yh[p] + swh * ghh);   // sw=0 masks borders
                h4 nv = clamp1(yv[p] + swv * gvh);
                yh[p] = nh; yv[p] = nv;
                h4 qh = swh * nh;                    // q = sigma*w*y
                h4 qv = swv * nv;
                qH[p] = qh;
                *(h4*)&sQV[bF] = qv;
                sQH3[bF >> 2] = qh[3];
            }
        }
    };

    // ---- primal: xn = fma(INV_DEN, xo, fma(TAUIS_ID, dv, ci)) in
    //      packed fp32 pairs; xt = 1.5xn - 0.5xo.
    //      last: store fp32 to global, skip LDS. ----
    const f2 kID  = {INV_DEN,  INV_DEN};
    const f2 kTS  = {TAUIS_ID, TAUIS_ID};
    const f2 k15  = {1.5f, 1.5f};
    const f2 km05 = {-0.5f, -0.5f};
    auto primal = [&](int rem, bool last) {
        #pragma unroll
        for (int p = 0; p < NPASS; ++p) {
            if (rem >= dth_[p]) {
                int u = tid + p * NT, bF = u * 4;
                int bu = (bF >= UPR * 4) ? bF - PC : bF;  // row-0 junk tolerated
                h4 qvu = *(const h4*)&sQV[bu];
                h4 qv  = *(const h4*)&sQV[bF];
                h4 civ = *(const h4*)&sCI[bF];
                uint32 qhl = *(const unsigned short*)&sQH3[imax(u - 1, 0)];
                uint2 qu = __builtin_bit_cast(uint2, qH[p]);
                h4 qsh = __builtin_bit_cast(h4,
                             make_uint2(abit(qu.x, qhl << 16), abit(qu.y, qu.x)));
                h4 dvg = (qH[p] - qsh) + (qv - qvu);     // v_pk_sub/add_f16
                f2 dv0 = {(float)dvg[0], (float)dvg[1]};
                f2 dv1 = {(float)dvg[2], (float)dvg[3]};
                f2 ci0 = {(float)civ[0], (float)civ[1]};
                f2 ci1 = {(float)civ[2], (float)civ[3]};
                f2 xo0 = xr2[p][0], xo1 = xr2[p][1];
                f2 xn0 = __builtin_elementwise_fma(kID, xo0,
                             __builtin_elementwise_fma(kTS, dv0, ci0));
                f2 xn1 = __builtin_elementwise_fma(kID, xo1,
                             __builtin_elementwise_fma(kTS, dv1, ci1));
                xr2[p][0] = xn0; xr2[p][1] = xn1;
                f2 xt0 = __builtin_elementwise_fma(k15, xn0, xo0 * km05);
                f2 xt1 = __builtin_elementwise_fma(k15, xn1, xo1 * km05);
                if (!last) {
                    h4 nx; nx[0] = (_Float16)xt0[0]; nx[1] = (_Float16)xt0[1];
                           nx[2] = (_Float16)xt1[0]; nx[3] = (_Float16)xt1[1];
                    xt16[p] = nx;
                    *(h4*)&sXT16[bF] = nx;
                } else {
                    int li = u / UPR, uj = u - li * UPR;
                    int gi = gr0 + li;
                    if (li >= 10 && uj >= 3 && uj <= 18 && gi < M) {
                        *(float4*)&out[(size_t)gi * N + (gc0 + uj * 4)] =
                            make_float4(xt0[0], xt0[1], xt1[0], xt1[1]);
                    }
                }
            }
        }
    };

    primal(9, false);          // t=0 (dual(0) fused into init)
    __syncthreads();
    #pragma unroll 1
    for (int t = 1; t < 10; ++t) {
        int rem = 9 - t;
        dual(rem);
        __syncthreads();
        primal(rem, t == 9);
        __syncthreads();
    }
}

extern "C" void kernel_launch(void* const* d_in, const int* in_sizes, int n_in,
                              void* d_out, int out_size, void* d_ws, size_t ws_size,
                              hipStream_t stream)
{
    const float* img = (const float*)d_in[0];
    const float* w1  = (const float*)d_in[1];
    const float* w2  = (const float*)d_in[2];
    float* out = (float*)d_out;

    dim3 grid(N / TW, GY);   // 32 x 32 = 1024 blocks = 2/CU x 512 slots
    pd_fused<<<grid, NT, 0, stream>>>(img, out, w1, w2);
}